// Round 1
// baseline (645.865 us; speedup 1.0000x reference)
//
#include <hip/hip_runtime.h>
#include <hip/hip_bf16.h>
#include <math.h>
#include <stdint.h>

// Problem constants
#define N_TOK   8192          // SL*BS
#define HS      1024
#define FFN     4096
#define NE      8
#define NA      16384         // N_TOK * TOPK
#define CAP     16384         // per-expert bucket capacity (worst case)
#define BM      128
#define BN      128
#define BK      32
#define MAXT    136           // max total M-tiles: 16384/128 + 8

typedef __attribute__((ext_vector_type(8))) short          bf16x8;
typedef __attribute__((ext_vector_type(4))) float          f32x4;
typedef __attribute__((ext_vector_type(4))) float          fvec4;
typedef __attribute__((ext_vector_type(4))) unsigned short usvec4;

__device__ __forceinline__ void gl_lds16(const void* g, void* l) {
  __builtin_amdgcn_global_load_lds(
      (const __attribute__((address_space(1))) unsigned int*)g,
      (__attribute__((address_space(3))) unsigned int*)l,
      16, 0, 0);
}

__device__ __forceinline__ unsigned short f2bf(float f) {
  union { float f; unsigned int u; } v; v.f = f;
  unsigned int r = v.u + 0x7FFFu + ((v.u >> 16) & 1u);
  return (unsigned short)(r >> 16);
}

// ---------------- conversion kernels ----------------

// x f32 [N_TOK][HS] -> bf16 same layout
__global__ void cvt_x_kernel(const fvec4* __restrict__ in, unsigned short* __restrict__ out, int n4) {
  int i = blockIdx.x * 256 + threadIdx.x;
  if (i >= n4) return;
  fvec4 v = in[i];
  usvec4 o;
  o[0] = f2bf(v[0]); o[1] = f2bf(v[1]); o[2] = f2bf(v[2]); o[3] = f2bf(v[3]);
  *(usvec4*)(out + (size_t)i * 4) = o;
}

// in [E][R][C] f32 -> out [E][C][R] bf16 (K-contiguous B^T layout for GEMM)
__global__ void tpose_cvt_kernel(const float* __restrict__ in, unsigned short* __restrict__ out,
                                 int R, int C) {
  __shared__ float t[64][65];
  int bc = blockIdx.x * 64, br = blockIdx.y * 64, e = blockIdx.z;
  const float* ine = in + (size_t)e * R * C;
  unsigned short* oute = out + (size_t)e * R * C;
  int tx = threadIdx.x & 63, ty = threadIdx.x >> 6;   // ty in [0,4)
#pragma unroll
  for (int q = 0; q < 16; ++q) {
    int r = ty * 16 + q;
    t[r][tx] = ine[(size_t)(br + r) * C + bc + tx];
  }
  __syncthreads();
#pragma unroll
  for (int q = 0; q < 16; ++q) {
    int c = ty * 16 + q;
    oute[(size_t)(bc + c) * R + br + tx] = f2bf(t[tx][c]);
  }
}

// ---------------- routing ----------------

__global__ void route_kernel(const int* __restrict__ idx, const float* __restrict__ wts,
                             int* __restrict__ counts, int* __restrict__ btok,
                             int* __restrict__ bslot, float* __restrict__ bw) {
  int a = blockIdx.x * 256 + threadIdx.x;
  if (a >= NA) return;
  int e = idx[a];
  int pos = atomicAdd(&counts[e], 1);
  btok[(size_t)e * CAP + pos]  = a >> 1;     // token id
  bslot[(size_t)e * CAP + pos] = a;          // destination slot in perm buffer
  bw[(size_t)e * CAP + pos]    = wts[a];
}

// single-thread: build M-tile table; counts[8] <- total tile count
__global__ void build_tiles_kernel(int* __restrict__ counts, int2* __restrict__ table) {
  if (threadIdx.x == 0 && blockIdx.x == 0) {
    int nt = 0;
    for (int e = 0; e < NE; ++e) {
      int c = counts[e];
      int t = (c + BM - 1) >> 7;
      for (int m = 0; m < t && nt < MAXT; ++m) table[nt++] = make_int2(e, m);
    }
    counts[8] = nt;
  }
}

// ---------------- GEMM 1: h = gelu(gather(x) @ w1[e]) ----------------
// A: gathered xb rows [rows][HS] bf16; B^T: w1T[e] [FFN][HS] bf16; C: h bf16 [tile*BM][FFN]
__global__ __launch_bounds__(256, 2)
void gemm1_kernel(const unsigned short* __restrict__ xb, const unsigned short* __restrict__ w1T,
                  unsigned short* __restrict__ h,
                  const int* __restrict__ btok, const int* __restrict__ counts,
                  const int2* __restrict__ table, int p0, int tc) {
  int nt = counts[8];
  int j = blockIdx.y;
  if (j < p0 || j >= p0 + tc || j >= nt) return;
  int2 te = table[j];
  int e = te.x, tm = te.y;
  int count = counts[e];
  int bn0 = blockIdx.x * BN;
  int slot = j - p0;

  __shared__ unsigned short As[BM * BK];
  __shared__ unsigned short Bs[BN * BK];

  int tid = threadIdx.x;
  int wave = tid >> 6, lane = tid & 63;
  int wr = wave >> 1, wc = wave & 1;

  const unsigned short* w1e = w1T + (size_t)e * FFN * HS;

  const char* srcA[2]; const char* srcB[2];
  unsigned short* dstA[2]; unsigned short* dstB[2];
#pragma unroll
  for (int jj = 0; jj < 2; ++jj) {
    int ch = wave * 2 + jj;                  // 0..7
    int row = ch * 16 + (lane >> 2);         // 0..127
    int grow = tm * BM + row;
    int tok = (grow < count) ? btok[(size_t)e * CAP + grow] : 0;
    srcA[jj] = (const char*)(xb + (size_t)tok * HS + (lane & 3) * 8);
    dstA[jj] = As + ch * 512;
    int nrow = bn0 + ch * 16 + (lane >> 2);
    srcB[jj] = (const char*)(w1e + (size_t)nrow * HS + (lane & 3) * 8);
    dstB[jj] = Bs + ch * 512;
  }

  f32x4 acc[4][4] = {};

  for (int k0 = 0; k0 < HS; k0 += BK) {
#pragma unroll
    for (int jj = 0; jj < 2; ++jj) {
      gl_lds16(srcA[jj] + (size_t)k0 * 2, dstA[jj]);
      gl_lds16(srcB[jj] + (size_t)k0 * 2, dstB[jj]);
    }
    __syncthreads();
    bf16x8 a[4], b[4];
#pragma unroll
    for (int i = 0; i < 4; ++i)
      a[i] = *(const bf16x8*)(As + (wr * 64 + i * 16 + (lane & 15)) * BK + (lane >> 4) * 8);
#pragma unroll
    for (int n = 0; n < 4; ++n)
      b[n] = *(const bf16x8*)(Bs + (wc * 64 + n * 16 + (lane & 15)) * BK + (lane >> 4) * 8);
#pragma unroll
    for (int i = 0; i < 4; ++i)
#pragma unroll
      for (int n = 0; n < 4; ++n)
        acc[i][n] = __builtin_amdgcn_mfma_f32_16x16x32_bf16(a[i], b[n], acc[i][n], 0, 0, 0);
    __syncthreads();
  }

  size_t hbase = (size_t)slot * BM;
#pragma unroll
  for (int i = 0; i < 4; ++i) {
    int rowb = wr * 64 + i * 16 + ((lane >> 4) << 2);
#pragma unroll
    for (int n = 0; n < 4; ++n) {
      int col = bn0 + wc * 64 + n * 16 + (lane & 15);
#pragma unroll
      for (int r = 0; r < 4; ++r) {
        float v = acc[i][n][r];
        float g = 0.5f * v * (1.0f + erff(v * 0.70710678118654752f));
        h[(hbase + rowb + r) * FFN + col] = f2bf(g);
      }
    }
  }
}

// ---------------- GEMM 2: perm[slot] = w * (h @ w2[e]) ----------------
__global__ __launch_bounds__(256, 2)
void gemm2_kernel(const unsigned short* __restrict__ h, const unsigned short* __restrict__ w2T,
                  float* __restrict__ perm,
                  const int* __restrict__ bslot, const float* __restrict__ bw,
                  const int* __restrict__ counts, const int2* __restrict__ table,
                  int p0, int tc) {
  int nt = counts[8];
  int j = blockIdx.y;
  if (j < p0 || j >= p0 + tc || j >= nt) return;
  int2 te = table[j];
  int e = te.x, tm = te.y;
  int count = counts[e];
  int bn0 = blockIdx.x * BN;
  int slotb = j - p0;

  __shared__ unsigned short As[BM * BK];
  __shared__ unsigned short Bs[BN * BK];

  int tid = threadIdx.x;
  int wave = tid >> 6, lane = tid & 63;
  int wr = wave >> 1, wc = wave & 1;

  const unsigned short* w2e = w2T + (size_t)e * HS * FFN;

  const char* srcA[2]; const char* srcB[2];
  unsigned short* dstA[2]; unsigned short* dstB[2];
#pragma unroll
  for (int jj = 0; jj < 2; ++jj) {
    int ch = wave * 2 + jj;
    int row = ch * 16 + (lane >> 2);
    srcA[jj] = (const char*)(h + ((size_t)slotb * BM + row) * FFN + (lane & 3) * 8);
    dstA[jj] = As + ch * 512;
    int nrow = bn0 + ch * 16 + (lane >> 2);
    srcB[jj] = (const char*)(w2e + (size_t)nrow * FFN + (lane & 3) * 8);
    dstB[jj] = Bs + ch * 512;
  }

  f32x4 acc[4][4] = {};

  for (int k0 = 0; k0 < FFN; k0 += BK) {
#pragma unroll
    for (int jj = 0; jj < 2; ++jj) {
      gl_lds16(srcA[jj] + (size_t)k0 * 2, dstA[jj]);
      gl_lds16(srcB[jj] + (size_t)k0 * 2, dstB[jj]);
    }
    __syncthreads();
    bf16x8 a[4], b[4];
#pragma unroll
    for (int i = 0; i < 4; ++i)
      a[i] = *(const bf16x8*)(As + (wr * 64 + i * 16 + (lane & 15)) * BK + (lane >> 4) * 8);
#pragma unroll
    for (int n = 0; n < 4; ++n)
      b[n] = *(const bf16x8*)(Bs + (wc * 64 + n * 16 + (lane & 15)) * BK + (lane >> 4) * 8);
#pragma unroll
    for (int i = 0; i < 4; ++i)
#pragma unroll
      for (int n = 0; n < 4; ++n)
        acc[i][n] = __builtin_amdgcn_mfma_f32_16x16x32_bf16(a[i], b[n], acc[i][n], 0, 0, 0);
    __syncthreads();
  }

#pragma unroll
  for (int i = 0; i < 4; ++i) {
    int rowb = wr * 64 + i * 16 + ((lane >> 4) << 2);
#pragma unroll
    for (int r = 0; r < 4; ++r) {
      int grow = tm * BM + rowb + r;
      if (grow < count) {
        int s = bslot[(size_t)e * CAP + grow];
        float wgt = bw[(size_t)e * CAP + grow];
#pragma unroll
        for (int n = 0; n < 4; ++n) {
          int col = bn0 + wc * 64 + n * 16 + (lane & 15);
          perm[(size_t)s * HS + col] = wgt * acc[i][n][r];
        }
      }
    }
  }
}

// ---------------- combine: out[t] = perm[2t] + perm[2t+1] ----------------
__global__ void combine_kernel(const fvec4* __restrict__ perm, fvec4* __restrict__ out, int n4) {
  int i = blockIdx.x * 256 + threadIdx.x;
  if (i >= n4) return;
  int t = i >> 8;            // HS/4 = 256 fvec4 per row
  int c = i & 255;
  out[i] = perm[(size_t)(2 * t) * 256 + c] + perm[(size_t)(2 * t + 1) * 256 + c];
}

// ---------------- host ----------------

extern "C" void kernel_launch(void* const* d_in, const int* in_sizes, int n_in,
                              void* d_out, int out_size, void* d_ws, size_t ws_size,
                              hipStream_t stream) {
  const float* x   = (const float*)d_in[0];
  const float* ew  = (const float*)d_in[1];
  // d_in[2] = scores (unused by reference output)
  const float* w1  = (const float*)d_in[3];
  const float* w2  = (const float*)d_in[4];
  const int*   eix = (const int*)d_in[5];

  char* ws = (char*)d_ws;
  const size_t o_w1T    = 0;                       // 67,108,864
  const size_t o_w2T    = 67108864ULL;             // 67,108,864
  const size_t o_xb     = 134217728ULL;            // 16,777,216
  const size_t o_btok   = 150994944ULL;            // 524,288
  const size_t o_bslot  = 151519232ULL;            // 524,288
  const size_t o_bw     = 152043520ULL;            // 524,288
  const size_t o_counts = 152567808ULL;            // 256
  const size_t o_table  = 152568064ULL;            // 1,280
  const size_t o_perm   = 152569344ULL;            // 67,108,864
  const size_t o_h      = 219678208ULL;            // up to 142,606,336

  unsigned short* w1T = (unsigned short*)(ws + o_w1T);
  unsigned short* w2T = (unsigned short*)(ws + o_w2T);
  unsigned short* xb  = (unsigned short*)(ws + o_xb);
  int*   btok   = (int*)(ws + o_btok);
  int*   bslot  = (int*)(ws + o_bslot);
  float* bw     = (float*)(ws + o_bw);
  int*   counts = (int*)(ws + o_counts);
  int2*  table  = (int2*)(ws + o_table);
  float* perm   = (float*)(ws + o_perm);
  unsigned short* hbuf = (unsigned short*)(ws + o_h);

  // h-buffer chunking if workspace is small
  long long havail = (long long)ws_size - (long long)o_h;
  long long tile_bytes = (long long)BM * FFN * 2;
  int tc = (int)(havail / tile_bytes);
  if (tc < 1) tc = 1;
  if (tc > MAXT) tc = MAXT;
  int npass = (MAXT + tc - 1) / tc;

  hipMemsetAsync(counts, 0, 256, stream);

  cvt_x_kernel<<<(N_TOK * HS / 4 + 255) / 256, 256, 0, stream>>>(
      (const fvec4*)x, xb, N_TOK * HS / 4);
  tpose_cvt_kernel<<<dim3(FFN / 64, HS / 64, NE), 256, 0, stream>>>(w1, w1T, HS, FFN);
  tpose_cvt_kernel<<<dim3(HS / 64, FFN / 64, NE), 256, 0, stream>>>(w2, w2T, FFN, HS);

  route_kernel<<<(NA + 255) / 256, 256, 0, stream>>>(eix, ew, counts, btok, bslot, bw);
  build_tiles_kernel<<<1, 64, 0, stream>>>(counts, table);

  for (int p = 0; p < npass; ++p) {
    gemm1_kernel<<<dim3(FFN / BN, MAXT), 256, 0, stream>>>(
        xb, w1T, hbuf, btok, counts, table, p * tc, tc);
    gemm2_kernel<<<dim3(HS / BN, MAXT), 256, 0, stream>>>(
        hbuf, w2T, perm, bslot, bw, counts, table, p * tc, tc);
  }

  combine_kernel<<<(N_TOK * HS / 4 + 255) / 256, 256, 0, stream>>>(
      (const fvec4*)perm, (fvec4*)d_out, N_TOK * HS / 4);
}